// Round 4
// baseline (40.890 us; speedup 1.0000x reference)
//
#include <hip/hip_runtime.h>

#define MCW_EPS 1e-32f

constexpr int NRED = 64;   // stage-2 reduction blocks
constexpr int U    = 4;    // row-groups per pipeline stage (4 float4-pairs)

// ---------------------------------------------------------------------------
// Stage 1: stream output+labels once.
// R4: explicit 2-deep software pipeline with ping-pong register buffers.
// R3's VGPR_Count=28 proved the compiler serialized the "unrolled" loads
// (4 float4 live = 16 regs + 14 accums didn't fit what it chose to keep).
// Now: 8 float4 loads (x[0..3], l[0..3] of the NEXT chunk) are issued as one
// clause and pinned above the current chunk's compute via sched_barrier(0).
// Steady state: 128 B/lane always in flight. launch_bounds(256,4) -> 128 VGPR
// budget so the ~96 live registers fit without spilling.
// Layout: row-major [B, 256]. Thread t owns columns c0=4*(t&63) of row (t>>6)
// in each 4-row group -> float4 loads, 16B/lane fully coalesced.
// ---------------------------------------------------------------------------
__global__ __launch_bounds__(256, 4) void mcwauc_main(
    const float* __restrict__ x_, const float* __restrict__ l_,
    int rowGroups, int nPairs,
    float* __restrict__ P_sp, float* __restrict__ P_sn,
    float* __restrict__ P_np, float* __restrict__ P_lg)
{
    const int t       = threadIdx.x;
    const int lane_rg = t >> 6;          // which of 4 rows in the row-group
    const int c0      = (t & 63) << 2;   // base column (4 consecutive cols)
    const size_t laneOff = (size_t)lane_rg * 256 + c0;

    float sp[4] = {0.f, 0.f, 0.f, 0.f};
    float sn[4] = {0.f, 0.f, 0.f, 0.f};
    float np[4] = {0.f, 0.f, 0.f, 0.f};
    float lp = 0.f, ln = 0.f;

    const int stride = gridDim.x * U;

#define MCW_LOAD(XB, LB, RG)                                                  \
    do {                                                                      \
        _Pragma("unroll")                                                     \
        for (int u = 0; u < U; ++u) {                                         \
            const size_t idx = (size_t)((RG) + u) * 1024 + laneOff;           \
            XB[u] = *reinterpret_cast<const float4*>(x_ + idx);               \
            LB[u] = *reinterpret_cast<const float4*>(l_ + idx);               \
        }                                                                     \
    } while (0)

#define MCW_COMPUTE(XB, LB)                                                   \
    do {                                                                      \
        _Pragma("unroll")                                                     \
        for (int u = 0; u < U; ++u) {                                         \
            _Pragma("unroll")                                                 \
            for (int k = 0; k < 4; ++k) {                                     \
                const float xw = (&XB[u].x)[k];                               \
                const float lw = (&LB[u].x)[k];   /* exactly 0.0f or 1.0f */  \
                const float e  = __expf(-xw);                                 \
                const float s  = __builtin_amdgcn_rcpf(1.f + e);              \
                const float s1 = e * s;           /* 1-sigmoid, no cancel */  \
                const float sel = (lw != 0.f) ? s : s1;                       \
                const float lg  = __logf(sel + MCW_EPS);                      \
                sp[k] = fmaf(lw, s, sp[k]);                                   \
                sn[k] += s - lw * s;                                          \
                np[k] += lw;                                                  \
                lp    = fmaf(lw, lg, lp);                                     \
                ln   += lg - lw * lg;                                         \
            }                                                                 \
        }                                                                     \
    } while (0)

    float4 xA[U], lA[U], xB[U], lB[U];
    int rg = blockIdx.x * U;

    if (nPairs > 0) {
        MCW_LOAD(xA, lA, rg);                       // prologue
        for (int p = 0; p < nPairs; ++p) {
            MCW_LOAD(xB, lB, rg + stride);          // next chunk in flight
            __builtin_amdgcn_sched_barrier(0);      // pin loads above compute
            MCW_COMPUTE(xA, lA);
            if (p + 1 < nPairs) {                   // uniform scalar branch
                MCW_LOAD(xA, lA, rg + 2 * stride);
                __builtin_amdgcn_sched_barrier(0);
            }
            MCW_COMPUTE(xB, lB);
            rg += 2 * stride;
        }
    }
    // generic tail (empty for the bench shape: rowGroups % (2*stride) == 0)
    for (int r = rg; r < rowGroups; r += stride) {
        MCW_LOAD(xA, lA, r);
        MCW_COMPUTE(xA, lA);
    }
#undef MCW_LOAD
#undef MCW_COMPUTE

    // ---- block reduce per-column partials (4 row-lanes -> 1 per column) ----
    __shared__ float rp[4][256];
    __shared__ float rn[4][256];
    __shared__ float rc[4][256];
    #pragma unroll
    for (int k = 0; k < 4; ++k) {
        rp[lane_rg][c0 + k] = sp[k];
        rn[lane_rg][c0 + k] = sn[k];
        rc[lane_rg][c0 + k] = np[k];
    }

    // ---- wave-reduce the global log sums while LDS settles ----
    #pragma unroll
    for (int o = 32; o > 0; o >>= 1) {
        lp += __shfl_down(lp, o);
        ln += __shfl_down(ln, o);
    }
    __shared__ float wl[2][4];
    if ((t & 63) == 0) { wl[0][t >> 6] = lp; wl[1][t >> 6] = ln; }

    __syncthreads();

    // ---- coalesced partial writes (no atomics) ----
    const size_t base = (size_t)blockIdx.x * 256;
    P_sp[base + t] = rp[0][t] + rp[1][t] + rp[2][t] + rp[3][t];
    P_sn[base + t] = rn[0][t] + rn[1][t] + rn[2][t] + rn[3][t];
    P_np[base + t] = rc[0][t] + rc[1][t] + rc[2][t] + rc[3][t];
    if (t == 0) {
        P_lg[2 * blockIdx.x + 0] = wl[0][0] + wl[0][1] + wl[0][2] + wl[0][3];
        P_lg[2 * blockIdx.x + 1] = wl[1][0] + wl[1][1] + wl[1][2] + wl[1][3];
    }
}

// ---------------------------------------------------------------------------
// Stage 2: fold G partials -> NRED partials, float4-vectorized.
// Block j reduces chunk consecutive partial records. 256 threads = 4 row
// slices x 64 lanes; lane owns columns 4*(t&63)..+3.
// ---------------------------------------------------------------------------
__global__ __launch_bounds__(256) void mcwauc_reduce(
    const float* __restrict__ P_sp, const float* __restrict__ P_sn,
    const float* __restrict__ P_np,
    float* __restrict__ Q_sp, float* __restrict__ Q_sn, float* __restrict__ Q_np,
    int chunk)
{
    const int j  = blockIdx.x;
    const int t  = threadIdx.x;
    const int pr = t >> 6;              // row slice within chunk
    const int c4 = (t & 63) << 2;       // float4 column base
    float4 a = {0.f, 0.f, 0.f, 0.f}, b = a, d = a;
    for (int p = pr; p < chunk; p += 4) {
        const size_t off = ((size_t)j * chunk + p) * 256 + c4;
        const float4 va = *reinterpret_cast<const float4*>(P_sp + off);
        const float4 vb = *reinterpret_cast<const float4*>(P_sn + off);
        const float4 vd = *reinterpret_cast<const float4*>(P_np + off);
        a.x += va.x; a.y += va.y; a.z += va.z; a.w += va.w;
        b.x += vb.x; b.y += vb.y; b.z += vb.z; b.w += vb.w;
        d.x += vd.x; d.y += vd.y; d.z += vd.z; d.w += vd.w;
    }
    __shared__ float4 ra[4][64], rb[4][64], rd[4][64];
    ra[pr][t & 63] = a; rb[pr][t & 63] = b; rd[pr][t & 63] = d;
    __syncthreads();
    if (pr == 0) {
        #pragma unroll
        for (int r = 1; r < 4; ++r) {
            const float4 va = ra[r][t], vb = rb[r][t], vd = rd[r][t];
            a.x += va.x; a.y += va.y; a.z += va.z; a.w += va.w;
            b.x += vb.x; b.y += vb.y; b.z += vb.z; b.w += vb.w;
            d.x += vd.x; d.y += vd.y; d.z += vd.z; d.w += vd.w;
        }
        const size_t q = (size_t)j * 256 + c4;
        *reinterpret_cast<float4*>(Q_sp + q) = a;
        *reinterpret_cast<float4*>(Q_sn + q) = b;
        *reinterpret_cast<float4*>(Q_np + q) = d;
    }
}

// ---------------------------------------------------------------------------
// Stage 3: 1 block x 256 threads (one per column). Fold NRED partials,
// per-column penalty branch, CEL, write the 2 outputs.
// ---------------------------------------------------------------------------
__global__ __launch_bounds__(256) void mcwauc_fin(
    const float* __restrict__ Q_sp, const float* __restrict__ Q_sn,
    const float* __restrict__ Q_np, const float* __restrict__ P_lg,
    float* __restrict__ out, int B, int G)
{
    const int c = threadIdx.x;
    float a = 0.f, b = 0.f, d = 0.f;
    #pragma unroll 8
    for (int j = 0; j < NRED; ++j) {
        const size_t off = (size_t)j * 256 + c;
        a += Q_sp[off];
        b += Q_sn[off];
        d += Q_np[off];
    }
    float lp = 0.f, ln = 0.f;
    for (int p = c; p < G; p += 256) {
        lp += P_lg[2 * p + 0];
        ln += P_lg[2 * p + 1];
    }

    const float np = d;
    const float nn = (float)B - np;
    const float mp = a / fmaxf(np, 1.f);
    const float mn = b / fmaxf(nn, 1.f);

    float pen;
    if (np > 0.f && nn > 0.f)      pen = 1.f - mp + mn;
    else if (np == 0.f)            pen = 1.f + mn;
    else                           pen = 1.f - mp;

    // reduce {pen, np, lp, ln} across the 256 threads
    float psum = pen, csum = np;
    #pragma unroll
    for (int o = 32; o > 0; o >>= 1) {
        psum += __shfl_down(psum, o);
        csum += __shfl_down(csum, o);
        lp   += __shfl_down(lp, o);
        ln   += __shfl_down(ln, o);
    }
    __shared__ float s4[4][4];
    if ((c & 63) == 0) {
        s4[0][c >> 6] = psum;
        s4[1][c >> 6] = csum;
        s4[2][c >> 6] = lp;
        s4[3][c >> 6] = ln;
    }
    __syncthreads();

    if (c == 255) out[1] = 0.1f * pen;   // penalty term of the LAST category
    if (c == 0) {
        const double pensum = (double)s4[0][0] + s4[0][1] + s4[0][2] + s4[0][3];
        const double numP   = (double)s4[1][0] + s4[1][1] + s4[1][2] + s4[1][3];
        const double L0     = (double)s4[2][0] + s4[2][1] + s4[2][2] + s4[2][3];
        const double L1     = (double)s4[3][0] + s4[3][1] + s4[3][2] + s4[3][3];
        const double total  = (double)B * 256.0;
        const double aP = numP / total;
        const double aN = 1.0 - aP;
        const double cel = -aN * (L0 / total) - aP * (L1 / total);
        out[0] = (float)(cel + 0.1 * (pensum / 256.0));
    }
}

extern "C" void kernel_launch(void* const* d_in, const int* in_sizes, int n_in,
                              void* d_out, int out_size, void* d_ws, size_t ws_size,
                              hipStream_t stream) {
    const float* x = (const float*)d_in[0];
    const float* l = (const float*)d_in[1];
    const int n = in_sizes[0];
    const int B = n / 256;
    const int rowGroups = B / 4;           // B = 65536 -> 16384

    // G = stage-1 grid (power of two, multiple of NRED), sized to ws.
    int G = 1024;                          // 4 blocks/CU at 128-VGPR budget
    auto need = [](int g) -> size_t {
        return (size_t)g * 768 * sizeof(float)       // P_sp/sn/np
             + (size_t)g * 2 * sizeof(float)         // P_lg
             + (size_t)NRED * 768 * sizeof(float);   // Q_sp/sn/np
    };
    while (G > NRED && need(G) > ws_size) G >>= 1;

    const int stride = G * U;
    const int nPairs = rowGroups / (2 * stride);  // full pipelined pairs/block

    float* P_sp = (float*)d_ws;
    float* P_sn = P_sp + (size_t)G * 256;
    float* P_np = P_sn + (size_t)G * 256;
    float* P_lg = P_np + (size_t)G * 256;
    float* Q_sp = P_lg + (size_t)G * 2;
    float* Q_sn = Q_sp + (size_t)NRED * 256;
    float* Q_np = Q_sn + (size_t)NRED * 256;

    mcwauc_main<<<G, 256, 0, stream>>>(x, l, rowGroups, nPairs,
                                       P_sp, P_sn, P_np, P_lg);
    mcwauc_reduce<<<NRED, 256, 0, stream>>>(P_sp, P_sn, P_np,
                                            Q_sp, Q_sn, Q_np, G / NRED);
    mcwauc_fin<<<1, 256, 0, stream>>>(Q_sp, Q_sn, Q_np, P_lg, (float*)d_out, B, G);
}

// Round 7
// 38.941 us; speedup vs baseline: 1.0500x; 1.0500x over previous
//
#include <hip/hip_runtime.h>

#define MCW_EPS 1e-32f

constexpr int NRED = 64;   // stage-2 reduction blocks

typedef __attribute__((address_space(3))) float lds_f;
typedef const __attribute__((address_space(1))) float glb_f;

// ---------------------------------------------------------------------------
// Stage 1: stream output+labels once.
// R7: deep prefetch via global_load_lds (direct-to-LDS DMA, NO VGPR dest).
// R4-R6 proved VGPR-destination prefetch can't be expressed reliably in HIP
// (compiler serializes C-level batches; asm outputs get copied/spilled before
// their in-flight loads land -> NaN/crash). global_load_lds sidesteps both:
// fire-and-forget, vmcnt-tracked, zero register pressure -> depth-3 pipeline.
// Per wave: private slab of 3 bufs x 2KB (1KB x + 1KB l). No barriers in the
// loop (wave-private). Counted s_waitcnt vmcnt(4) per iter (never 0 until
// drain), sched_barrier(0) after each wait (rule #18).
// Layout: row-major [B,256]. Rowgroup = 4 rows = 1024 floats. Wave w covers
// floats [w*256,(w+1)*256) of each rowgroup; lane ln takes 16B at ln*4.
// Thread t = 64w+ln -> row w, cols 4*ln..+3 (same epilogue mapping as R3).
// Chunk i of block b = rowgroup b + i*gridDim.x.
// ---------------------------------------------------------------------------
__global__ __launch_bounds__(256) void mcwauc_main(
    const float* __restrict__ x_, const float* __restrict__ l_,
    int rowGroups,
    float* __restrict__ P_sp, float* __restrict__ P_sn,
    float* __restrict__ P_np, float* __restrict__ P_lg)
{
    const int t   = threadIdx.x;
    const int wv  = t >> 6;            // wave id 0..3 (= row in rowgroup)
    const int ln  = t & 63;            // lane
    const int c0  = ln << 2;           // base column (4 consecutive cols)
    const int bid = blockIdx.x;
    const int gsz = gridDim.x;

    __shared__ float slab[6144];       // 4 waves x 3 bufs x 512 floats = 24KB
    __shared__ float wl[2][4];
    const int waveBase = wv * 1536;    // floats
    const int wvOff    = wv << 8;      // wave's float offset within rowgroup

    float sp[4] = {0.f, 0.f, 0.f, 0.f};
    float ts[4] = {0.f, 0.f, 0.f, 0.f};
    float np[4] = {0.f, 0.f, 0.f, 0.f};
    float lp = 0.f, lsum = 0.f;

    int nCh = 0;
    if (bid < rowGroups)
        nCh = (rowGroups - bid + gsz - 1) / gsz;

#define MCW_STAGE(CI, BO)                                                     \
    do {                                                                      \
        const size_t goff = ((size_t)bid + (size_t)(CI) * gsz) * 1024         \
                          + wvOff + (ln << 2);                                \
        lds_f* _d = (lds_f*)(slab + waveBase + (BO) * 512);                   \
        __builtin_amdgcn_global_load_lds((glb_f*)(x_ + goff), _d,       16, 0, 0); \
        __builtin_amdgcn_global_load_lds((glb_f*)(l_ + goff), _d + 256, 16, 0, 0); \
    } while (0)

#define MCW_WAITV(N) do {                                                     \
        asm volatile("s_waitcnt vmcnt(" #N ")" ::: "memory");                 \
        __builtin_amdgcn_sched_barrier(0); } while (0)
#define MCW_WAITL do {                                                        \
        asm volatile("s_waitcnt lgkmcnt(0)" ::: "memory");                    \
        __builtin_amdgcn_sched_barrier(0); } while (0)

    // prologue: fill the pipe (up to 3 chunks in flight)
    if (nCh > 0) MCW_STAGE(0, 0);
    if (nCh > 1) MCW_STAGE(1, 1);
    if (nCh > 2) MCW_STAGE(2, 2);

    int bo = 0;
    for (int i = 0; i < nCh; ++i) {
        const int rem = nCh - i;                    // wave-uniform
        if (rem >= 3)      { MCW_WAITV(4); }        // oldest of 3 landed
        else if (rem == 2) { MCW_WAITV(2); }
        else               { MCW_WAITV(0); }

        const float4 xv = *reinterpret_cast<const float4*>(
            &slab[waveBase + bo * 512 + c0]);
        const float4 lv = *reinterpret_cast<const float4*>(
            &slab[waveBase + bo * 512 + 256 + c0]);
        MCW_WAITL;                                  // reads landed in regs

        if (i + 3 < nCh) MCW_STAGE(i + 3, bo);      // refill just-freed buf

        #pragma unroll
        for (int k = 0; k < 4; ++k) {
            const float xw = (&xv.x)[k];
            const float lw = (&lv.x)[k];            // exactly 0.0f or 1.0f
            const float e  = __expf(-xw);
            const float r  = __builtin_amdgcn_rcpf(1.f + e);   // sigmoid
            const float s1 = e * r;                 // 1-sigmoid, no cancel
            const float sel = (lw != 0.f) ? r : s1;
            const float lg  = __logf(sel + MCW_EPS);
            ts[k] += r;
            sp[k]  = fmaf(lw, r, sp[k]);
            np[k] += lw;
            lsum  += lg;
            lp     = fmaf(lw, lg, lp);
        }
        bo = (bo == 2) ? 0 : bo + 1;
    }
#undef MCW_STAGE
#undef MCW_WAITV
#undef MCW_WAITL

    // ---- wave-reduce the global log sums ----
    #pragma unroll
    for (int o = 32; o > 0; o >>= 1) {
        lp   += __shfl_down(lp, o);
        lsum += __shfl_down(lsum, o);
    }
    if (ln == 0) { wl[0][wv] = lp; wl[1][wv] = lsum; }

    // ---- epilogue: reuse slab (all DMA drained by final vmcnt(0)) ----
    __syncthreads();
    float* red = slab;                 // [4][256] row-major

    #pragma unroll
    for (int k = 0; k < 4; ++k) red[(wv << 8) + c0 + k] = sp[k];
    __syncthreads();
    const float a = red[t] + red[256 + t] + red[512 + t] + red[768 + t];
    __syncthreads();

    #pragma unroll
    for (int k = 0; k < 4; ++k) red[(wv << 8) + c0 + k] = ts[k];
    __syncthreads();
    const float tsu = red[t] + red[256 + t] + red[512 + t] + red[768 + t];
    __syncthreads();

    #pragma unroll
    for (int k = 0; k < 4; ++k) red[(wv << 8) + c0 + k] = np[k];
    __syncthreads();
    const float d = red[t] + red[256 + t] + red[512 + t] + red[768 + t];

    // ---- coalesced partial writes (no atomics) ----
    const size_t base = (size_t)bid * 256;
    P_sp[base + t] = a;
    P_sn[base + t] = tsu - a;          // sum s over neg
    P_np[base + t] = d;
    if (t == 0) {
        const float L0 = wl[0][0] + wl[0][1] + wl[0][2] + wl[0][3];  // pos logs
        const float LS = wl[1][0] + wl[1][1] + wl[1][2] + wl[1][3];  // all logs
        P_lg[2 * bid + 0] = L0;
        P_lg[2 * bid + 1] = LS - L0;                                 // neg logs
    }
}

// ---------------------------------------------------------------------------
// Stage 2: fold G partials -> NRED partials, float4-vectorized.
// ---------------------------------------------------------------------------
__global__ __launch_bounds__(256) void mcwauc_reduce(
    const float* __restrict__ P_sp, const float* __restrict__ P_sn,
    const float* __restrict__ P_np,
    float* __restrict__ Q_sp, float* __restrict__ Q_sn, float* __restrict__ Q_np,
    int chunk)
{
    const int j  = blockIdx.x;
    const int t  = threadIdx.x;
    const int pr = t >> 6;              // row slice within chunk
    const int c4 = (t & 63) << 2;       // float4 column base
    float4 a = {0.f, 0.f, 0.f, 0.f}, b = a, d = a;
    for (int p = pr; p < chunk; p += 4) {
        const size_t off = ((size_t)j * chunk + p) * 256 + c4;
        const float4 va = *reinterpret_cast<const float4*>(P_sp + off);
        const float4 vb = *reinterpret_cast<const float4*>(P_sn + off);
        const float4 vd = *reinterpret_cast<const float4*>(P_np + off);
        a.x += va.x; a.y += va.y; a.z += va.z; a.w += va.w;
        b.x += vb.x; b.y += vb.y; b.z += vb.z; b.w += vb.w;
        d.x += vd.x; d.y += vd.y; d.z += vd.z; d.w += vd.w;
    }
    __shared__ float4 ra[4][64], rb[4][64], rd[4][64];
    ra[pr][t & 63] = a; rb[pr][t & 63] = b; rd[pr][t & 63] = d;
    __syncthreads();
    if (pr == 0) {
        #pragma unroll
        for (int r = 1; r < 4; ++r) {
            const float4 va = ra[r][t], vb = rb[r][t], vd = rd[r][t];
            a.x += va.x; a.y += va.y; a.z += va.z; a.w += va.w;
            b.x += vb.x; b.y += vb.y; b.z += vb.z; b.w += vb.w;
            d.x += vd.x; d.y += vd.y; d.z += vd.z; d.w += vd.w;
        }
        const size_t q = (size_t)j * 256 + c4;
        *reinterpret_cast<float4*>(Q_sp + q) = a;
        *reinterpret_cast<float4*>(Q_sn + q) = b;
        *reinterpret_cast<float4*>(Q_np + q) = d;
    }
}

// ---------------------------------------------------------------------------
// Stage 3: 1 block x 256 threads (one per column). Fold NRED partials,
// per-column penalty branch, CEL, write the 2 outputs.
// ---------------------------------------------------------------------------
__global__ __launch_bounds__(256) void mcwauc_fin(
    const float* __restrict__ Q_sp, const float* __restrict__ Q_sn,
    const float* __restrict__ Q_np, const float* __restrict__ P_lg,
    float* __restrict__ out, int B, int G)
{
    const int c = threadIdx.x;
    float a = 0.f, b = 0.f, d = 0.f;
    #pragma unroll 8
    for (int j = 0; j < NRED; ++j) {
        const size_t off = (size_t)j * 256 + c;
        a += Q_sp[off];
        b += Q_sn[off];
        d += Q_np[off];
    }
    float lp = 0.f, ln = 0.f;
    for (int p = c; p < G; p += 256) {
        lp += P_lg[2 * p + 0];
        ln += P_lg[2 * p + 1];
    }

    const float np = d;
    const float nn = (float)B - np;
    const float mp = a / fmaxf(np, 1.f);
    const float mn = b / fmaxf(nn, 1.f);

    float pen;
    if (np > 0.f && nn > 0.f)      pen = 1.f - mp + mn;
    else if (np == 0.f)            pen = 1.f + mn;
    else                           pen = 1.f - mp;

    // reduce {pen, np, lp, ln} across the 256 threads
    float psum = pen, csum = np;
    #pragma unroll
    for (int o = 32; o > 0; o >>= 1) {
        psum += __shfl_down(psum, o);
        csum += __shfl_down(csum, o);
        lp   += __shfl_down(lp, o);
        ln   += __shfl_down(ln, o);
    }
    __shared__ float s4[4][4];
    if ((c & 63) == 0) {
        s4[0][c >> 6] = psum;
        s4[1][c >> 6] = csum;
        s4[2][c >> 6] = lp;
        s4[3][c >> 6] = ln;
    }
    __syncthreads();

    if (c == 255) out[1] = 0.1f * pen;   // penalty term of the LAST category
    if (c == 0) {
        const double pensum = (double)s4[0][0] + s4[0][1] + s4[0][2] + s4[0][3];
        const double numP   = (double)s4[1][0] + s4[1][1] + s4[1][2] + s4[1][3];
        const double L0     = (double)s4[2][0] + s4[2][1] + s4[2][2] + s4[2][3];
        const double L1     = (double)s4[3][0] + s4[3][1] + s4[3][2] + s4[3][3];
        const double total  = (double)B * 256.0;
        const double aP = numP / total;
        const double aN = 1.0 - aP;
        const double cel = -aN * (L0 / total) - aP * (L1 / total);
        out[0] = (float)(cel + 0.1 * (pensum / 256.0));
    }
}

extern "C" void kernel_launch(void* const* d_in, const int* in_sizes, int n_in,
                              void* d_out, int out_size, void* d_ws, size_t ws_size,
                              hipStream_t stream) {
    const float* x = (const float*)d_in[0];
    const float* l = (const float*)d_in[1];
    const int n = in_sizes[0];
    const int B = n / 256;
    const int rowGroups = B / 4;           // B = 65536 -> 16384

    // G = stage-1 grid: 1536 = 6 blocks/CU at 24KB LDS; multiple of NRED.
    int G = 1536;
    auto need = [](int g) -> size_t {
        return (size_t)g * 768 * sizeof(float)       // P_sp/sn/np
             + (size_t)g * 2 * sizeof(float)         // P_lg
             + (size_t)NRED * 768 * sizeof(float);   // Q_sp/sn/np
    };
    while (G > NRED && need(G) > ws_size) G >>= 1;

    float* P_sp = (float*)d_ws;
    float* P_sn = P_sp + (size_t)G * 256;
    float* P_np = P_sn + (size_t)G * 256;
    float* P_lg = P_np + (size_t)G * 256;
    float* Q_sp = P_lg + (size_t)G * 2;
    float* Q_sn = Q_sp + (size_t)NRED * 256;
    float* Q_np = Q_sn + (size_t)NRED * 256;

    mcwauc_main<<<G, 256, 0, stream>>>(x, l, rowGroups,
                                       P_sp, P_sn, P_np, P_lg);
    mcwauc_reduce<<<NRED, 256, 0, stream>>>(P_sp, P_sn, P_np,
                                            Q_sp, Q_sn, Q_np, G / NRED);
    mcwauc_fin<<<1, 256, 0, stream>>>(Q_sp, Q_sn, Q_np, P_lg, (float*)d_out, B, G);
}